// Round 6
// baseline (255.752 us; speedup 1.0000x reference)
//
#include <hip/hip_runtime.h>
#include <hip/hip_bf16.h>

// ---------------------------------------------------------------------------
// Int8-quantized 3x3 conv, stride 1, pad 1.
//   x: (32,128,56,56) f32   w: (256,128,3,3) f32   bias: (256,) f32
//   out: (32,256,56,56) f32
// R1: same-address atomicMax = 106 us -> block partials.
// R3: conv latency-bound at occ 17% (156 regs -> 2 waves/SIMD tier).
// R4: backend bug: v_mul_f32 with two SGPR srcs; force one into VGPR.
// R5: occ 43% but still 80 us, MfmaUtil 15% -> occupancy wasn't binding;
//   8-MFMA steps vs ~300cy overhead/step + LDS demand ~ MFMA floor.
// R6: acc[4][4] (wave 64px x 64ch): 4 A ds_reads feed 16 MFMAs (2x A-reuse,
//   halved B traffic), zero-pad tile keeps masks out, target VGPR<=64 so
//   64 AGPR + VGPR stays in the <=128 tier (4 waves/SIMD). + XCD swizzle,
//   merged absmax launch.
// ---------------------------------------------------------------------------

typedef int v4i __attribute__((ext_vector_type(4)));

#define NBATCH 32
#define CIN    128
#define HW     56
#define PIX    (HW*HW)            // 3136
#define COUT   256
#define XTOT   (NBATCH*CIN*PIX)   // 12,845,056
#define WTOT   (COUT*CIN*9)       // 294,912

// ---------------- abs-max partials: x (blocks 0..1791) + w (1792..1863) ----
__global__ __launch_bounds__(256) void absmax_both_kernel(
    const float* __restrict__ x, const float* __restrict__ w,
    float* __restrict__ px, float* __restrict__ pw)
{
    const int bid = blockIdx.x;
    float m = 0.f;
    if (bid < 1792) {
        const float4* in4 = (const float4*)x;
        const int t = bid * 256 + threadIdx.x;
        const int stride = 1792 * 256;
#pragma unroll
        for (int k = 0; k < 7; ++k) {      // 3,211,264 float4 exactly
            float4 v = in4[t + k * stride];
            m = fmaxf(m, fmaxf(fmaxf(fabsf(v.x), fabsf(v.y)),
                               fmaxf(fabsf(v.z), fabsf(v.w))));
        }
    } else {
        const float4* in4 = (const float4*)w;
        const int t = (bid - 1792) * 256 + threadIdx.x;
        const int stride = 72 * 256;
#pragma unroll
        for (int k = 0; k < 4; ++k) {      // 73,728 float4 exactly
            float4 v = in4[t + k * stride];
            m = fmaxf(m, fmaxf(fmaxf(fabsf(v.x), fabsf(v.y)),
                               fmaxf(fabsf(v.z), fabsf(v.w))));
        }
    }
#pragma unroll
    for (int off = 32; off >= 1; off >>= 1)
        m = fmaxf(m, __shfl_xor(m, off, 64));
    __shared__ float wmax[4];
    const int lane = threadIdx.x & 63, wid = threadIdx.x >> 6;
    if (lane == 0) wmax[wid] = m;
    __syncthreads();
    if (threadIdx.x == 0) {
        float r = fmaxf(fmaxf(wmax[0], wmax[1]), fmaxf(wmax[2], wmax[3]));
        if (bid < 1792) px[bid] = r; else pw[bid - 1792] = r;
    }
}

// ---------------- finalize: reduce partials -> scales (1 block) -------------
__global__ __launch_bounds__(256) void finalize_kernel(
    const float* __restrict__ px, const float* __restrict__ pw,
    float* __restrict__ scales)
{
    const int tid = threadIdx.x;
    float mxv = 0.f, mwv = 0.f;
#pragma unroll
    for (int k = 0; k < 7; ++k)
        mxv = fmaxf(mxv, px[k * 256 + tid]);   // 1792 partials exactly
    if (tid < 72) mwv = pw[tid];
#pragma unroll
    for (int off = 32; off >= 1; off >>= 1) {
        mxv = fmaxf(mxv, __shfl_xor(mxv, off, 64));
        mwv = fmaxf(mwv, __shfl_xor(mwv, off, 64));
    }
    __shared__ float sx[4], sw[4];
    const int lane = tid & 63, wid = tid >> 6;
    if (lane == 0) { sx[wid] = mxv; sw[wid] = mwv; }
    __syncthreads();
    if (tid == 0) {
        float fx = fmaxf(fmaxf(sx[0], sx[1]), fmaxf(sx[2], sx[3]));
        float fw = fmaxf(fmaxf(sw[0], sw[1]), fmaxf(sw[2], sw[3]));
        scales[0] = fmaxf(fx / 127.0f, 1e-8f);
        scales[1] = fmaxf(fw / 127.0f, 1e-8f);
    }
}

// ---------------- quantize weights into [khw][o][c] int8 --------------------
__global__ void quant_w_kernel(const float* __restrict__ w,
                               const float* __restrict__ scales,
                               signed char* __restrict__ qw) {
    float s = scales[1];
    int idx = blockIdx.x * blockDim.x + threadIdx.x;
    if (idx >= WTOT) return;
    int o   = idx / (CIN * 9);
    int rem = idx % (CIN * 9);
    int c   = rem / 9;
    int khw = rem % 9;
    float q = rintf(w[idx] / s);
    q = fminf(127.0f, fmaxf(-127.0f, q));
    qw[khw * (COUT * CIN) + o * CIN + c] = (signed char)(int)q;
}

// ---------------- quantize x: NCHW f32 -> NHWC int8 (float4 loads) ----------
__global__ __launch_bounds__(256) void quant_x_kernel(const float* __restrict__ x,
                                                      const float* __restrict__ scales,
                                                      signed char* __restrict__ qx) {
    __shared__ signed char lds[32 * 132];   // 32 pixels x 128 c, row pad 132
    float s = scales[0];
    const int n   = blockIdx.y;
    const int p0  = blockIdx.x * 32;
    const int tid = threadIdx.x;
#pragma unroll
    for (int i = 0; i < 4; ++i) {
        int idx = i * 256 + tid;          // 1024 float4 = 128c x 8 pixel-quads
        int c   = idx >> 3;
        int pq  = idx & 7;
        float4 v = *(const float4*)&x[((size_t)(n * CIN + c)) * PIX + p0 + pq * 4];
        float qv[4] = {v.x, v.y, v.z, v.w};
#pragma unroll
        for (int j = 0; j < 4; ++j) {
            float q = rintf(qv[j] / s);
            q = fminf(127.0f, fmaxf(-127.0f, q));
            lds[(pq * 4 + j) * 132 + c] = (signed char)(int)q;
        }
    }
    __syncthreads();
#pragma unroll
    for (int i = 0; i < 4; ++i) {
        int idx = i * 256 + tid;          // 1024 int4-words
        int pp  = idx >> 5;
        int cw  = (idx & 31) * 4;
        *(int*)&qx[((size_t)(n * PIX + p0 + pp)) * CIN + cw] =
            *(const int*)&lds[pp * 132 + cw];
    }
}

// ---------------- conv: implicit GEMM, 64 px x 256 ch per block -------------
// A: zero-padded 2D tile [4 h-rows][58 w][128B] in LDS (29 KB), XOR-swizzled
//    (byte ^= (r&7)<<4); padding baked as zeros -> no masks in K-loop.
// Wave = 64 px x 64 ch: acc[4][4] (64 AGPR); 4 A ds_reads feed 16 MFMAs per
// kc-step. B single-buffered from L2-resident qw, loads issued first.
// Target VGPR <= 64 so AGPR+VGPR <= 128 -> 4 waves/SIMD.
__global__ __launch_bounds__(256, 4) void conv_kernel(
    const signed char* __restrict__ qx,
    const signed char* __restrict__ qw,
    const float* __restrict__ bias,
    const float* __restrict__ scales,
    float* __restrict__ out)
{
    __shared__ signed char lds[232 * 128];   // 29,696 B
    const int tid  = threadIdx.x;
    const int lane = tid & 63;
    const int wid  = tid >> 6;     // 0..3 -> channel quarter
    const int prow = lane & 15;    // fragment row (pixel for A, channel for B)
    const int klo  = lane >> 4;    // K sub-chunk (x16B)

    // XCD-aware bijective swizzle: 1568 % 8 == 0, 196 blocks per XCD chunk
    const int bid = (blockIdx.x & 7) * 196 + (blockIdx.x >> 3);
    const int n   = bid / 49;
    const int p0  = (bid % 49) * 64;
    const int hbase = p0 / HW - 1;

    const size_t xbase = (size_t)n * PIX * CIN;

    // ---- stage A: 232 LDS-rows (4 h x 58 w) x 128B, zeros in pads ----
#pragma unroll
    for (int it = 0; it < 8; ++it) {
        int chunk = it * 256 + tid;            // 1856 chunks of 16B
        if (chunk < 232 * 8) {
            int r  = chunk >> 3;
            int cb = (chunk & 7) * 16;
            int hr = r / 58;
            int wc = r - hr * 58;
            int h  = hbase + hr;
            int w  = wc - 1;
            bool valid = ((unsigned)h < HW) && ((unsigned)w < HW);
            int p = valid ? (h * HW + w) : 0;  // clamped addr, value masked
            v4i v = *(const v4i*)(qx + xbase + (size_t)p * CIN + cb);
            if (!valid) v = (v4i){0, 0, 0, 0};
            *(v4i*)&lds[r * 128 + (cb ^ ((r & 7) << 4))] = v;
        }
    }
    __syncthreads();

    // per-s LDS row base (dh=0, dw=0)
    int rr[4];
#pragma unroll
    for (int s = 0; s < 4; ++s) {
        int p = p0 + s * 16 + prow;
        int h = p / HW, w = p - h * HW;
        rr[s] = (h - hbase) * 58 + (w + 1);
    }

    const int ch0     = wid * 64;
    const int colbase = klo * 16;

    v4i acc[4][4] = {};

    // B base for this wave: channel ch0+prow, K-offset colbase
    const signed char* b0ptr = qw + (size_t)(ch0 + prow) * CIN + colbase;

#pragma unroll
    for (int khw = 0; khw < 9; ++khw) {
        const int rofs = (khw / 3 - 1) * 58 + (khw % 3 - 1);
        const signed char* bk = b0ptr + (size_t)khw * (COUT * CIN);
#pragma unroll
        for (int kc = 0; kc < 2; ++kc) {
            // B loads first (L2-resident; compiler may hoist across steps)
            v4i b[4];
#pragma unroll
            for (int t = 0; t < 4; ++t)
                b[t] = *(const v4i*)(bk + kc * 64 + (size_t)t * 16 * CIN);
            const int col = kc * 64 + colbase;
            v4i a[4];
#pragma unroll
            for (int s = 0; s < 4; ++s) {
                int r = rr[s] + rofs;
                a[s] = *(const v4i*)&lds[r * 128 + (col ^ ((r & 7) << 4))];
            }
#pragma unroll
            for (int s = 0; s < 4; ++s)
#pragma unroll
                for (int t = 0; t < 4; ++t)
                    acc[s][t] = __builtin_amdgcn_mfma_i32_16x16x64_i8(
                        a[s], b[t], acc[s][t], 0, 0, 0);
        }
    }

    // ---- epilogue: dequant + bias, float4 stores ----
    float s0 = scales[0], s1 = scales[1];
    asm volatile("" : "+v"(s0));   // force VGPR: two-SGPR v_mul is illegal
    const float comb = s0 * s1;
    const size_t obase = (size_t)n * COUT * PIX;
#pragma unroll
    for (int t = 0; t < 4; ++t) {
        int ch = ch0 + t * 16 + prow;
        float bs = bias[ch];
#pragma unroll
        for (int s = 0; s < 4; ++s) {
            int p = p0 + s * 16 + klo * 4;
            float4 v;
            v.x = (float)acc[s][t].x * comb + bs;
            v.y = (float)acc[s][t].y * comb + bs;
            v.z = (float)acc[s][t].z * comb + bs;
            v.w = (float)acc[s][t].w * comb + bs;
            *(float4*)&out[obase + (size_t)ch * PIX + p] = v;
        }
    }
}

// ---------------------------------------------------------------------------
extern "C" void kernel_launch(void* const* d_in, const int* in_sizes, int n_in,
                              void* d_out, int out_size, void* d_ws, size_t ws_size,
                              hipStream_t stream) {
    const float* x    = (const float*)d_in[0];
    const float* w    = (const float*)d_in[1];
    const float* bias = (const float*)d_in[2];
    float* out = (float*)d_out;

    // ws layout: scales (2 f32) @0; px (1792 f32) @256; pw (72 f32) @7680;
    // qx @8192 (12.85 MB); qw after.
    float*       scales = (float*)d_ws;
    float*       px     = (float*)((char*)d_ws + 256);
    float*       pw     = (float*)((char*)d_ws + 7680);
    signed char* qx     = (signed char*)d_ws + 8192;
    signed char* qw     = qx + (size_t)XTOT;

    absmax_both_kernel<<<1864, 256, 0, stream>>>(x, w, px, pw);
    finalize_kernel<<<1, 256, 0, stream>>>(px, pw, scales);
    quant_w_kernel<<<WTOT / 256, 256, 0, stream>>>(w, scales, qw);
    quant_x_kernel<<<dim3(98, 32), 256, 0, stream>>>(x, scales, qx);
    conv_kernel<<<1568, 256, 0, stream>>>(qx, qw, bias, scales, out);
}

// Round 7
// 199.085 us; speedup vs baseline: 1.2846x; 1.2846x over previous
//
#include <hip/hip_runtime.h>
#include <hip/hip_bf16.h>

// ---------------------------------------------------------------------------
// Int8-quantized 3x3 conv, stride 1, pad 1.
//   x: (32,128,56,56) f32   w: (256,128,3,3) f32   bias: (256,) f32
//   out: (32,256,56,56) f32
// R1: same-address atomicMax = 106 us -> block partials.
// R3: conv latency-bound at occ 17% (156 regs -> 2 waves/SIMD tier).
// R4: backend bug: v_mul_f32 with two SGPR srcs; force one into VGPR.
// R5: occ 43% but 80 us, MfmaUtil 15% -> per-step B L2-latency not hidden.
// R6 FAILED: 64px x 256ch acc[4][4] + XCD swizzle -> 118 us. WRITE_SIZE
//   doubled (100->193 MB, swizzle-correlated; reverted) and VGPR=64 left no
//   prefetch headroom (serial B-load->MFMA chain, MfmaUtil 9.7%).
// R7: R5 shape (64px x 128ch, acc[4][2]) + B staged per-khw in LDS (16 KB
//   XOR-swizzled slab, software-pipelined loads: slab k+1 issued under
//   slab k's compute). ds_read ~12cy replaces ~300-500cy L2 B-loads.
// ---------------------------------------------------------------------------

typedef int v4i __attribute__((ext_vector_type(4)));

#define NBATCH 32
#define CIN    128
#define HW     56
#define PIX    (HW*HW)            // 3136
#define COUT   256
#define XTOT   (NBATCH*CIN*PIX)   // 12,845,056
#define WTOT   (COUT*CIN*9)       // 294,912

// ---------------- abs-max partials: x (blocks 0..1791) + w (1792..1863) ----
__global__ __launch_bounds__(256) void absmax_both_kernel(
    const float* __restrict__ x, const float* __restrict__ w,
    float* __restrict__ px, float* __restrict__ pw)
{
    const int bid = blockIdx.x;
    float m = 0.f;
    if (bid < 1792) {
        const float4* in4 = (const float4*)x;
        const int t = bid * 256 + threadIdx.x;
        const int stride = 1792 * 256;
#pragma unroll
        for (int k = 0; k < 7; ++k) {      // 3,211,264 float4 exactly
            float4 v = in4[t + k * stride];
            m = fmaxf(m, fmaxf(fmaxf(fabsf(v.x), fabsf(v.y)),
                               fmaxf(fabsf(v.z), fabsf(v.w))));
        }
    } else {
        const float4* in4 = (const float4*)w;
        const int t = (bid - 1792) * 256 + threadIdx.x;
        const int stride = 72 * 256;
#pragma unroll
        for (int k = 0; k < 4; ++k) {      // 73,728 float4 exactly
            float4 v = in4[t + k * stride];
            m = fmaxf(m, fmaxf(fmaxf(fabsf(v.x), fabsf(v.y)),
                               fmaxf(fabsf(v.z), fabsf(v.w))));
        }
    }
#pragma unroll
    for (int off = 32; off >= 1; off >>= 1)
        m = fmaxf(m, __shfl_xor(m, off, 64));
    __shared__ float wmax[4];
    const int lane = threadIdx.x & 63, wid = threadIdx.x >> 6;
    if (lane == 0) wmax[wid] = m;
    __syncthreads();
    if (threadIdx.x == 0) {
        float r = fmaxf(fmaxf(wmax[0], wmax[1]), fmaxf(wmax[2], wmax[3]));
        if (bid < 1792) px[bid] = r; else pw[bid - 1792] = r;
    }
}

// ---------------- finalize: reduce partials -> scales (1 block) -------------
__global__ __launch_bounds__(256) void finalize_kernel(
    const float* __restrict__ px, const float* __restrict__ pw,
    float* __restrict__ scales)
{
    const int tid = threadIdx.x;
    float mxv = 0.f, mwv = 0.f;
#pragma unroll
    for (int k = 0; k < 7; ++k)
        mxv = fmaxf(mxv, px[k * 256 + tid]);   // 1792 partials exactly
    if (tid < 72) mwv = pw[tid];
#pragma unroll
    for (int off = 32; off >= 1; off >>= 1) {
        mxv = fmaxf(mxv, __shfl_xor(mxv, off, 64));
        mwv = fmaxf(mwv, __shfl_xor(mwv, off, 64));
    }
    __shared__ float sx[4], sw[4];
    const int lane = tid & 63, wid = tid >> 6;
    if (lane == 0) { sx[wid] = mxv; sw[wid] = mwv; }
    __syncthreads();
    if (tid == 0) {
        float fx = fmaxf(fmaxf(sx[0], sx[1]), fmaxf(sx[2], sx[3]));
        float fw = fmaxf(fmaxf(sw[0], sw[1]), fmaxf(sw[2], sw[3]));
        scales[0] = fmaxf(fx / 127.0f, 1e-8f);
        scales[1] = fmaxf(fw / 127.0f, 1e-8f);
    }
}

// ---------------- quantize weights into [khw][o][c] int8 --------------------
__global__ void quant_w_kernel(const float* __restrict__ w,
                               const float* __restrict__ scales,
                               signed char* __restrict__ qw) {
    float s = scales[1];
    int idx = blockIdx.x * blockDim.x + threadIdx.x;
    if (idx >= WTOT) return;
    int o   = idx / (CIN * 9);
    int rem = idx % (CIN * 9);
    int c   = rem / 9;
    int khw = rem % 9;
    float q = rintf(w[idx] / s);
    q = fminf(127.0f, fmaxf(-127.0f, q));
    qw[khw * (COUT * CIN) + o * CIN + c] = (signed char)(int)q;
}

// ---------------- quantize x: NCHW f32 -> NHWC int8 (float4 loads) ----------
__global__ __launch_bounds__(256) void quant_x_kernel(const float* __restrict__ x,
                                                      const float* __restrict__ scales,
                                                      signed char* __restrict__ qx) {
    __shared__ signed char lds[32 * 132];   // 32 pixels x 128 c, row pad 132
    float s = scales[0];
    const int n   = blockIdx.y;
    const int p0  = blockIdx.x * 32;
    const int tid = threadIdx.x;
#pragma unroll
    for (int i = 0; i < 4; ++i) {
        int idx = i * 256 + tid;          // 1024 float4 = 128c x 8 pixel-quads
        int c   = idx >> 3;
        int pq  = idx & 7;
        float4 v = *(const float4*)&x[((size_t)(n * CIN + c)) * PIX + p0 + pq * 4];
        float qv[4] = {v.x, v.y, v.z, v.w};
#pragma unroll
        for (int j = 0; j < 4; ++j) {
            float q = rintf(qv[j] / s);
            q = fminf(127.0f, fmaxf(-127.0f, q));
            lds[(pq * 4 + j) * 132 + c] = (signed char)(int)q;
        }
    }
    __syncthreads();
#pragma unroll
    for (int i = 0; i < 4; ++i) {
        int idx = i * 256 + tid;          // 1024 int4-words
        int pp  = idx >> 5;
        int cw  = (idx & 31) * 4;
        *(int*)&qx[((size_t)(n * PIX + p0 + pp)) * CIN + cw] =
            *(const int*)&lds[pp * 132 + cw];
    }
}

// ---------------- conv: implicit GEMM, 64 px x 128 ch per block -------------
// A: zero-padded [4h][58w][128B] tile (29.7 KB), XOR-swizzled; staged once.
// B: per-khw 16 KB slab (128 ch x 128 K-bytes) in LDS, XOR-swizzled,
//    software-pipelined (slab k+1 global loads issue under slab k compute).
// Wave = 64 px x 32 ch, acc[4][2] = 32 AGPR. Paired blocks (nh) share A.
__global__ __launch_bounds__(256, 4) void conv_kernel(
    const signed char* __restrict__ qx,
    const signed char* __restrict__ qw,
    const float* __restrict__ bias,
    const float* __restrict__ scales,
    float* __restrict__ out)
{
    __shared__ signed char ldsA[232 * 128];   // 29,696 B
    __shared__ signed char ldsB[128 * 128];   // 16,384 B
    const int tid  = threadIdx.x;
    const int lane = tid & 63;
    const int wid  = tid >> 6;     // 0..3
    const int prow = lane & 15;    // fragment row (pixel for A, channel for B)
    const int klo  = lane >> 4;    // K sub-chunk (x16B)

    const int bid = blockIdx.x;    // 3136 blocks, no XCD swizzle (R6 lesson)
    const int nh  = bid & 1;       // channel half; pairs share the A-tile
    const int mt  = bid >> 1;      // 0..1567
    const int n   = mt / 49;
    const int p0  = (mt % 49) * 64;
    const int hbase = p0 / HW - 1;

    const size_t xbase = (size_t)n * PIX * CIN;

    // ---- stage A: 232 LDS-rows (4 h x 58 w) x 128B, zeros in pads ----
#pragma unroll
    for (int it = 0; it < 8; ++it) {
        int chunk = it * 256 + tid;            // 1856 chunks of 16B
        if (chunk < 232 * 8) {
            int r  = chunk >> 3;
            int cb = (chunk & 7) * 16;
            int hr = r / 58;
            int wc = r - hr * 58;
            int h  = hbase + hr;
            int w  = wc - 1;
            bool valid = ((unsigned)h < HW) && ((unsigned)w < HW);
            int p = valid ? (h * HW + w) : 0;  // clamped addr, value masked
            v4i v = *(const v4i*)(qx + xbase + (size_t)p * CIN + cb);
            if (!valid) v = (v4i){0, 0, 0, 0};
            *(v4i*)&ldsA[r * 128 + (cb ^ ((r & 7) << 4))] = v;
        }
    }

    // per-s LDS row base (dh=0, dw=0)
    int rr[4];
#pragma unroll
    for (int s = 0; s < 4; ++s) {
        int p = p0 + s * 16 + prow;
        int h = p / HW, w = p - h * HW;
        rr[s] = (h - hbase) * 58 + (w + 1);
    }

    const int chl0    = wid * 32;              // local channel base
    const int colbase = klo * 16;
    const signed char* wbase = qw + (size_t)nh * 128 * CIN;

    // this thread's 4 B-slab chunks: chunk = it*256+tid -> row r, byte cb
    int brow[4], bcol[4];
#pragma unroll
    for (int it = 0; it < 4; ++it) {
        int chunk = it * 256 + tid;
        brow[it] = chunk >> 3;
        bcol[it] = (chunk & 7) * 16;
    }

    v4i acc[4][2] = {};

    // prologue: load slab khw=0 into regs
    v4i breg[4];
#pragma unroll
    for (int it = 0; it < 4; ++it)
        breg[it] = *(const v4i*)(wbase + (size_t)brow[it] * CIN + bcol[it]);

#pragma unroll
    for (int khw = 0; khw < 9; ++khw) {
        __syncthreads();                       // prev slab consumed (also A-stage for khw=0)
#pragma unroll
        for (int it = 0; it < 4; ++it)
            *(v4i*)&ldsB[brow[it] * 128 + (bcol[it] ^ ((brow[it] & 7) << 4))] = breg[it];
        __syncthreads();                       // slab ready

        if (khw < 8) {                         // issue next slab under compute
            const signed char* bk = wbase + (size_t)(khw + 1) * (COUT * CIN);
#pragma unroll
            for (int it = 0; it < 4; ++it)
                breg[it] = *(const v4i*)(bk + (size_t)brow[it] * CIN + bcol[it]);
        }

        const int rofs = (khw / 3 - 1) * 58 + (khw % 3 - 1);
#pragma unroll
        for (int kc = 0; kc < 2; ++kc) {
            const int col = kc * 64 + colbase;
            v4i b[2];
#pragma unroll
            for (int t = 0; t < 2; ++t) {
                int chl = chl0 + t * 16 + prow;
                b[t] = *(const v4i*)&ldsB[chl * 128 + (col ^ ((chl & 7) << 4))];
            }
            v4i a[4];
#pragma unroll
            for (int s = 0; s < 4; ++s) {
                int r = rr[s] + rofs;
                a[s] = *(const v4i*)&ldsA[r * 128 + (col ^ ((r & 7) << 4))];
            }
#pragma unroll
            for (int s = 0; s < 4; ++s) {
                acc[s][0] = __builtin_amdgcn_mfma_i32_16x16x64_i8(a[s], b[0], acc[s][0], 0, 0, 0);
                acc[s][1] = __builtin_amdgcn_mfma_i32_16x16x64_i8(a[s], b[1], acc[s][1], 0, 0, 0);
            }
        }
    }

    // ---- epilogue: dequant + bias, float4 stores ----
    float s0 = scales[0], s1 = scales[1];
    asm volatile("" : "+v"(s0));   // force VGPR: two-SGPR v_mul is illegal
    const float comb = s0 * s1;
    const size_t obase = (size_t)n * COUT * PIX;
#pragma unroll
    for (int t = 0; t < 2; ++t) {
        int ch = nh * 128 + chl0 + t * 16 + prow;
        float bs = bias[ch];
#pragma unroll
        for (int s = 0; s < 4; ++s) {
            int p = p0 + s * 16 + klo * 4;
            float4 v;
            v.x = (float)acc[s][t].x * comb + bs;
            v.y = (float)acc[s][t].y * comb + bs;
            v.z = (float)acc[s][t].z * comb + bs;
            v.w = (float)acc[s][t].w * comb + bs;
            *(float4*)&out[obase + (size_t)ch * PIX + p] = v;
        }
    }
}

// ---------------------------------------------------------------------------
extern "C" void kernel_launch(void* const* d_in, const int* in_sizes, int n_in,
                              void* d_out, int out_size, void* d_ws, size_t ws_size,
                              hipStream_t stream) {
    const float* x    = (const float*)d_in[0];
    const float* w    = (const float*)d_in[1];
    const float* bias = (const float*)d_in[2];
    float* out = (float*)d_out;

    // ws layout: scales (2 f32) @0; px (1792 f32) @256; pw (72 f32) @7680;
    // qx @8192 (12.85 MB); qw after.
    float*       scales = (float*)d_ws;
    float*       px     = (float*)((char*)d_ws + 256);
    float*       pw     = (float*)((char*)d_ws + 7680);
    signed char* qx     = (signed char*)d_ws + 8192;
    signed char* qw     = qx + (size_t)XTOT;

    absmax_both_kernel<<<1864, 256, 0, stream>>>(x, w, px, pw);
    finalize_kernel<<<1, 256, 0, stream>>>(px, pw, scales);
    quant_w_kernel<<<WTOT / 256, 256, 0, stream>>>(w, scales, qw);
    quant_x_kernel<<<dim3(98, 32), 256, 0, stream>>>(x, scales, qx);
    conv_kernel<<<3136, 256, 0, stream>>>(qx, qw, bias, scales, out);
}